// Round 1
// baseline (152.877 us; speedup 1.0000x reference)
//
#include <hip/hip_runtime.h>
#include <math.h>

// MLSWAT neuron forward, T=4 steps.
// Shapes: input [4, 16, 2048, 768] f32, raw_threshes [4] f32, zero_point [1] f32.
// out[t, s] = spike(v_t[s]) - aux, with v recurrence per spatial site s.
//
// Exactness strategy: everything in the per-element path is IEEE f32
// add/sub/compare (bit-reproducible, no multiplies -> no FMA contraction
// hazard). The only transcendental is softplus on the 4 raw thresholds;
// we replicate numpy/jax logaddexp(x,0) staged rounding:
//   t1 = expf(-|x|)   (round to f32)
//   t2 = log1pf(t1)   (round to f32)
//   sp = max(x,0)+t2  (f32 add)
// emulating correctly-rounded f32 expf/log1pf via double-precision eval.

static constexpr int TT = 4;
static constexpr int NSPAT = 16 * 2048 * 768;   // 25,165,824 spatial sites
static constexpr int N4 = NSPAT / 4;            // float4 granularity

__global__ void compute_th_kernel(const float* __restrict__ raw,
                                  const float* __restrict__ zp,
                                  float* __restrict__ ws) {
    if (threadIdx.x == 0 && blockIdx.x == 0) {
        float inc[4];
#pragma unroll
        for (int i = 0; i < 4; ++i) {
            float x = raw[i];
            // softplus(x) = logaddexp(x, 0) = max(x,0) + log1p(exp(-|x|)),
            // with f32 rounding after each stage (matches np.logaddexp /
            // jax.nn.softplus on f32).
            float a = -fabsf(x);
            float e = (float)exp((double)a);     // correctly-rounded f32 exp
            float l = (float)log1p((double)e);   // correctly-rounded f32 log1p
            inc[i] = fmaxf(x, 0.0f) + l;
        }
        // cumsum (ascending), then flip -> descending thresholds
        float c0 = inc[0];
        float c1 = c0 + inc[1];
        float c2 = c1 + inc[2];
        float c3 = c2 + inc[3];
        ws[0] = c3;   // th[0] = largest
        ws[1] = c2;
        ws[2] = c1;
        ws[3] = c0;   // th[3] = smallest
        ws[4] = zp[0] / 4.0f;   // aux = zero_point / T (exact: /2^2)
    }
}

__device__ __forceinline__ float step1(float& v, float x, float aux,
                                       float th0, float th1, float th2,
                                       float th3) {
    // v = stop_grad(v) + x + aux, left-associated like the reference
    v = (v + x) + aux;
    // spike = first (largest) threshold with v >= th_i, else 0
    float s = (v >= th0) ? th0
            : (v >= th1) ? th1
            : (v >= th2) ? th2
            : (v >= th3) ? th3
            : 0.0f;
    v = v - s;          // soft reset
    return s - aux;     // emitted output
}

__global__ __launch_bounds__(256) void mlswat_fwd_kernel(
        const float* __restrict__ x,
        float* __restrict__ out,
        const float* __restrict__ ws) {
    const int i = blockIdx.x * blockDim.x + threadIdx.x;
    if (i >= N4) return;
    const float th0 = ws[0], th1 = ws[1], th2 = ws[2], th3 = ws[3];
    const float aux = ws[4];

    const float4* __restrict__ xin = (const float4*)x;
    float4* __restrict__ o = (float4*)out;

    float va = 0.5f, vb = 0.5f, vc = 0.5f, vd = 0.5f;   // INITIAL_MEM
#pragma unroll
    for (int t = 0; t < TT; ++t) {
        float4 xv = xin[(size_t)t * N4 + i];
        float4 r;
        r.x = step1(va, xv.x, aux, th0, th1, th2, th3);
        r.y = step1(vb, xv.y, aux, th0, th1, th2, th3);
        r.z = step1(vc, xv.z, aux, th0, th1, th2, th3);
        r.w = step1(vd, xv.w, aux, th0, th1, th2, th3);
        o[(size_t)t * N4 + i] = r;
    }
}

extern "C" void kernel_launch(void* const* d_in, const int* in_sizes, int n_in,
                              void* d_out, int out_size, void* d_ws, size_t ws_size,
                              hipStream_t stream) {
    const float* x   = (const float*)d_in[0];   // [4,16,2048,768] f32
    const float* raw = (const float*)d_in[1];   // [4] f32
    const float* zp  = (const float*)d_in[2];   // [1] f32
    float* out = (float*)d_out;
    float* ws  = (float*)d_ws;                  // [5] f32: th0..th3, aux

    compute_th_kernel<<<1, 64, 0, stream>>>(raw, zp, ws);

    const int threads = 256;
    const int blocks = (N4 + threads - 1) / threads;
    mlswat_fwd_kernel<<<blocks, threads, 0, stream>>>(x, out, ws);
}

// Round 3
// 150.097 us; speedup vs baseline: 1.0185x; 1.0185x over previous
//
#include <hip/hip_runtime.h>
#include <math.h>

// MLSWAT neuron forward, T=4 steps.
// Shapes: input [4, 16, 2048, 768] f32, raw_threshes [4] f32, zero_point [1] f32.
// out[t, s] = spike(v_t[s]) - aux, with v recurrence per spatial site s.
//
// Exactness: per-element path is IEEE f32 add/sub/compare only (bit-exact,
// no FMA hazard). Softplus on the 4 raw thresholds replicates numpy/jax
// logaddexp(x,0) staged rounding via double-precision exp/log1p rounded to f32.
//
// R1: 152.9 us, 5.27 TB/s effective (memory-bound, ceiling ~6.3).
// R2: nontemporal hints + 2x float4 per thread. Use clang ext_vector_type
//     (HIP_vector_type class is rejected by __builtin_nontemporal_*).

static constexpr int TT = 4;
static constexpr int NSPAT = 16 * 2048 * 768;   // 25,165,824 spatial sites
static constexpr int N4 = NSPAT / 4;            // float4 granularity
static constexpr int HALF = N4 / 2;             // per-thread second stream offset

typedef float f32x4 __attribute__((ext_vector_type(4)));

__global__ void compute_th_kernel(const float* __restrict__ raw,
                                  const float* __restrict__ zp,
                                  float* __restrict__ ws) {
    if (threadIdx.x == 0 && blockIdx.x == 0) {
        float inc[4];
#pragma unroll
        for (int i = 0; i < 4; ++i) {
            float x = raw[i];
            float a = -fabsf(x);
            float e = (float)exp((double)a);     // correctly-rounded f32 exp
            float l = (float)log1p((double)e);   // correctly-rounded f32 log1p
            inc[i] = fmaxf(x, 0.0f) + l;
        }
        float c0 = inc[0];
        float c1 = c0 + inc[1];
        float c2 = c1 + inc[2];
        float c3 = c2 + inc[3];
        ws[0] = c3;   // th[0] = largest (descending)
        ws[1] = c2;
        ws[2] = c1;
        ws[3] = c0;
        ws[4] = zp[0] / 4.0f;   // aux = zero_point / T (exact: /2^2)
    }
}

__device__ __forceinline__ float step1(float& v, float x, float aux,
                                       float th0, float th1, float th2,
                                       float th3) {
    v = (v + x) + aux;   // left-associated like the reference
    float s = (v >= th0) ? th0
            : (v >= th1) ? th1
            : (v >= th2) ? th2
            : (v >= th3) ? th3
            : 0.0f;
    v = v - s;           // soft reset
    return s - aux;
}

__device__ __forceinline__ f32x4 step4(f32x4& v, f32x4 xv, float aux,
                                       float t0, float t1, float t2, float t3) {
    f32x4 r;
#pragma unroll
    for (int k = 0; k < 4; ++k) {
        float vv = v[k];
        r[k] = step1(vv, xv[k], aux, t0, t1, t2, t3);
        v[k] = vv;
    }
    return r;
}

__global__ __launch_bounds__(256) void mlswat_fwd_kernel(
        const float* __restrict__ x,
        float* __restrict__ out,
        const float* __restrict__ ws) {
    const int i = blockIdx.x * blockDim.x + threadIdx.x;
    if (i >= HALF) return;
    const float th0 = ws[0], th1 = ws[1], th2 = ws[2], th3 = ws[3];
    const float aux = ws[4];

    const f32x4* __restrict__ xin = (const f32x4*)x;
    f32x4* __restrict__ o = (f32x4*)out;

    f32x4 va = {0.5f, 0.5f, 0.5f, 0.5f};   // INITIAL_MEM
    f32x4 vb = va;
#pragma unroll
    for (int t = 0; t < TT; ++t) {
        const size_t base = (size_t)t * N4;
        f32x4 xa = __builtin_nontemporal_load(&xin[base + i]);
        f32x4 xb = __builtin_nontemporal_load(&xin[base + i + HALF]);
        f32x4 ra = step4(va, xa, aux, th0, th1, th2, th3);
        f32x4 rb = step4(vb, xb, aux, th0, th1, th2, th3);
        __builtin_nontemporal_store(ra, &o[base + i]);
        __builtin_nontemporal_store(rb, &o[base + i + HALF]);
    }
}

extern "C" void kernel_launch(void* const* d_in, const int* in_sizes, int n_in,
                              void* d_out, int out_size, void* d_ws, size_t ws_size,
                              hipStream_t stream) {
    const float* x   = (const float*)d_in[0];   // [4,16,2048,768] f32
    const float* raw = (const float*)d_in[1];   // [4] f32
    const float* zp  = (const float*)d_in[2];   // [1] f32
    float* out = (float*)d_out;
    float* ws  = (float*)d_ws;                  // [5] f32: th0..th3, aux

    compute_th_kernel<<<1, 64, 0, stream>>>(raw, zp, ws);

    const int threads = 256;
    const int blocks = (HALF + threads - 1) / threads;
    mlswat_fwd_kernel<<<blocks, threads, 0, stream>>>(x, out, ws);
}